// Round 8
// baseline (271.577 us; speedup 1.0000x reference)
//
#include <hip/hip_runtime.h>
#include <hip/hip_bf16.h>
#include <stdint.h>

#define B_     16
#define T_     128
#define L_     100
#define IN_    100
#define EMB_   100
#define FEAT_  400
#define HID_   128
#define OUT_   50
#define RNNIN_ 500
#define VOCAB_ 10002
#define BT_    2048
#define TBLK   157   // ceil(VOCAB_/64)

// fp8 e4m3 HW-convert availability (gfx950). Fallback = bf16 tables.
#if defined(__has_builtin)
#if __has_builtin(__builtin_amdgcn_cvt_pk_f32_fp8) && __has_builtin(__builtin_amdgcn_cvt_pk_fp8_f32)
#define HAVE_FP8 1
#endif
#endif
#ifndef HAVE_FP8
#define HAVE_FP8 0
#endif

typedef __attribute__((ext_vector_type(8))) short short8;
typedef __attribute__((ext_vector_type(4))) short short4v;
typedef __attribute__((ext_vector_type(4))) float f32x4;
typedef __attribute__((ext_vector_type(2))) float v2f;

__device__ __forceinline__ float lo2f(unsigned int u) {
    union { unsigned int i; float f; } v; v.i = u << 16; return v.f;
}
__device__ __forceinline__ float hi2f(unsigned int u) {
    union { unsigned int i; float f; } v; v.i = u & 0xffff0000u; return v.f;
}
__device__ __forceinline__ float fast_tanh(float x) {
    x = fminf(15.f, fmaxf(-15.f, x));
    float e = __expf(2.f * x);
    return (e - 1.f) * __builtin_amdgcn_rcpf(e + 1.f);
}
__device__ __forceinline__ float sigm(float x) {
    x = fminf(30.f, fmaxf(-30.f, x));
    float e = __expf(-x);
    return __builtin_amdgcn_rcpf(1.f + e);
}

// ---------- casts: all bf16 staging buffers, one launch ----------
__global__ __launch_bounds__(256) void casts_k(
    const float* __restrict__ EN, const float* __restrict__ EP,
    const float* __restrict__ x, const float* __restrict__ Wt,
    const float* __restrict__ Wih, const float* __restrict__ Whh,
    __hip_bfloat16* __restrict__ ENb, __hip_bfloat16* __restrict__ EPb,
    __hip_bfloat16* __restrict__ x_bf, __hip_bfloat16* __restrict__ WtT,
    __hip_bfloat16* __restrict__ Wih_bf, __hip_bfloat16* __restrict__ Whh_bf)
{
    int t0 = blockIdx.x * 256 + threadIdx.x;
    const int stride = 256 * 256;
    int n1 = VOCAB_ * 100;
    for (int i = t0; i < n1; i += stride) ENb[i] = __float2bfloat16(EN[i]);
    for (int i = t0; i < n1; i += stride) EPb[i] = __float2bfloat16(EP[i]);
    for (int i = t0; i < BT_ * 100; i += stride) {
        int bt = i / 100, d = i - bt * 100;
        x_bf[i] = __float2bfloat16(x[(size_t)bt * 400 + d]);
    }
    // WtT[w][n][k] = Wt[w*100+k][n]  (k<100, zero-padded to 128), w=0..3
    for (int i = t0; i < 4 * 400 * 128; i += stride) {
        int w = i / (400 * 128), rem = i - w * 400 * 128;
        int n = rem >> 7, k = rem & 127;
        WtT[i] = __float2bfloat16((k < 100) ? Wt[(size_t)(w * 100 + k) * 400 + n] : 0.f);
    }
    // Wih_bf[g][k] (k<500, zero-padded to 512)
    for (int i = t0; i < 512 * 512; i += stride) {
        int g = i >> 9, k = i & 511;
        Wih_bf[i] = __float2bfloat16((k < 500) ? Wih[(size_t)g * 500 + k] : 0.f);
    }
    for (int i = t0; i < 512 * 128; i += stride) Whh_bf[i] = __float2bfloat16(Whh[i]);
}

// ---------- A-frag loader for K=100 row-major bf16 (4 K-slices, tail padded) ----------
__device__ __forceinline__ void load_a100(const __hip_bfloat16* __restrict__ arow,
                                          int kg, short8 af[4])
{
    af[0] = *(const short8*)(arow + kg * 8);
    af[1] = *(const short8*)(arow + 32 + kg * 8);
    af[2] = *(const short8*)(arow + 64 + kg * 8);
    short8 z = {};
    af[3] = z;
    if (kg == 0) {
        short4v t = *(const short4v*)(arow + 96);
        af[3][0] = t[0]; af[3][1] = t[1]; af[3][2] = t[2]; af[3][3] = t[3];
    }
}

// ---------- MFMA GEMMs: 3 table transforms (fp8/bf16 out) + q (f32 out) ----------
// Mapping (HW-verified via lstm_k since R3):
//   A[m=l&15][k=(l>>4)*8+j], B[n=l&15][k=(l>>4)*8+j], D[m=(l>>4)*4+r][n=l&15].
__global__ __launch_bounds__(256) void mm_k(
    const __hip_bfloat16* __restrict__ ENb, const __hip_bfloat16* __restrict__ EPb,
    const __hip_bfloat16* __restrict__ x_bf, const __hip_bfloat16* __restrict__ WtT,
    const float* __restrict__ btb,
    void* __restrict__ Es, void* __restrict__ Ee, void* __restrict__ Ep,
    float* __restrict__ q)
{
    int blk = blockIdx.x, tid = threadIdx.x;
    int wave = tid >> 6, lane = tid & 63;
    int cl = lane & 15, kg = lane >> 4;

    if (blk < 3 * TBLK) {
        int which = blk / TBLK, mb = blk - which * TBLK;
        const __hip_bfloat16* A = (which == 2) ? EPb : ENb;
        void* outp = (which == 0) ? Es : ((which == 1) ? Ee : Ep);
        int r0 = mb * 64 + wave * 16;
        int ra = r0 + cl; if (ra > VOCAB_ - 1) ra = VOCAB_ - 1;   // clamp; stores guarded
        short8 af[4];
        load_a100(A + (size_t)ra * 100, kg, af);
        const __hip_bfloat16* Bp = WtT + (size_t)which * 400 * 128;
        for (int n0 = 0; n0 < 25; n0++) {
            const __hip_bfloat16* brow = Bp + (size_t)(n0 * 16 + cl) * 128 + kg * 8;
            f32x4 acc = (f32x4){0.f, 0.f, 0.f, 0.f};
            acc = __builtin_amdgcn_mfma_f32_16x16x32_bf16(af[0], *(const short8*)(brow), acc, 0, 0, 0);
            acc = __builtin_amdgcn_mfma_f32_16x16x32_bf16(af[1], *(const short8*)(brow + 32), acc, 0, 0, 0);
            acc = __builtin_amdgcn_mfma_f32_16x16x32_bf16(af[2], *(const short8*)(brow + 64), acc, 0, 0, 0);
            acc = __builtin_amdgcn_mfma_f32_16x16x32_bf16(af[3], *(const short8*)(brow + 96), acc, 0, 0, 0);
            int colj = n0 * 16 + cl;
#pragma unroll
            for (int r = 0; r < 4; r++) {
                int gr = r0 + kg * 4 + r;
                if (gr < VOCAB_) {
                    float v = acc[r];
#if HAVE_FP8
                    unsigned u = (unsigned)__builtin_amdgcn_cvt_pk_fp8_f32(v, v, 0, false);
                    ((unsigned char*)outp)[(size_t)gr * 400 + colj] = (unsigned char)(u & 0xff);
#else
                    ((__hip_bfloat16*)outp)[(size_t)gr * 400 + colj] = __float2bfloat16(v);
#endif
                }
            }
        }
    } else {
        int mb = blk - 3 * TBLK;            // 0..31, M=2048
        int r0 = mb * 64 + wave * 16;
        short8 af[4];
        load_a100(x_bf + (size_t)(r0 + cl) * 100, kg, af);
        const __hip_bfloat16* Bp = WtT + (size_t)3 * 400 * 128;
        for (int n0 = 0; n0 < 25; n0++) {
            const __hip_bfloat16* brow = Bp + (size_t)(n0 * 16 + cl) * 128 + kg * 8;
            f32x4 acc = (f32x4){0.f, 0.f, 0.f, 0.f};
            acc = __builtin_amdgcn_mfma_f32_16x16x32_bf16(af[0], *(const short8*)(brow), acc, 0, 0, 0);
            acc = __builtin_amdgcn_mfma_f32_16x16x32_bf16(af[1], *(const short8*)(brow + 32), acc, 0, 0, 0);
            acc = __builtin_amdgcn_mfma_f32_16x16x32_bf16(af[2], *(const short8*)(brow + 64), acc, 0, 0, 0);
            acc = __builtin_amdgcn_mfma_f32_16x16x32_bf16(af[3], *(const short8*)(brow + 96), acc, 0, 0, 0);
            int colj = n0 * 16 + cl;
            float bb = btb[colj];
#pragma unroll
            for (int r = 0; r < 4; r++) {
                int gr = r0 + kg * 4 + r;
                q[(size_t)gr * 400 + colj] = acc[r] + bb;
            }
        }
    }
}

// ---------- stage A: ctx[bt][l] = sum_j tanh(Es+Ee+Ep+q)*Wa ----------
__global__ __launch_bounds__(256) void stage_a(
    const float* __restrict__ x,
    const void* __restrict__ Esv, const void* __restrict__ Eev,
    const void* __restrict__ Epv,
    const float* __restrict__ q, const float* __restrict__ Wa,
    float* __restrict__ ctx)
{
    __shared__ int idx_s[300];
    int bt = blockIdx.x, tid = threadIdx.x;
    const float* xr = x + (size_t)bt * 400 + 100;
    for (int i = tid; i < 300; i += 256) idx_s[i] = (int)xr[i];
    int lane = tid & 63, wave = tid >> 6;
    bool act = lane < 50;
    int j0 = lane * 8;
    float qv[8], wv[8];
    if (act) {
        float4 qa = *(const float4*)(q + (size_t)bt * 400 + j0);
        float4 qb = *(const float4*)(q + (size_t)bt * 400 + j0 + 4);
        float4 wa = *(const float4*)(Wa + j0);
        float4 wb = *(const float4*)(Wa + j0 + 4);
        qv[0]=qa.x; qv[1]=qa.y; qv[2]=qa.z; qv[3]=qa.w;
        qv[4]=qb.x; qv[5]=qb.y; qv[6]=qb.z; qv[7]=qb.w;
        wv[0]=wa.x; wv[1]=wa.y; wv[2]=wa.z; wv[3]=wa.w;
        wv[4]=wb.x; wv[5]=wb.y; wv[6]=wb.z; wv[7]=wb.w;
    } else {
#pragma unroll
        for (int jj = 0; jj < 8; jj++) { qv[jj] = 0.f; wv[jj] = 0.f; }
    }
    __syncthreads();
    for (int l = wave; l < 100; l += 4) {
        int i0 = idx_s[3 * l], i1 = idx_s[3 * l + 1], i2 = idx_s[3 * l + 2];
        float sum = 0.f;
        if (act) {
            float zs[8];
#if HAVE_FP8
            const unsigned char* Es8 = (const unsigned char*)Esv;
            const unsigned char* Ee8 = (const unsigned char*)Eev;
            const unsigned char* Ep8 = (const unsigned char*)Epv;
            uint2 a  = ((const uint2*)(Es8 + (size_t)i0 * 400))[lane];
            uint2 b  = ((const uint2*)(Ee8 + (size_t)i2 * 400))[lane];
            uint2 cc = ((const uint2*)(Ep8 + (size_t)i1 * 400))[lane];
            v2f s01 = __builtin_amdgcn_cvt_pk_f32_fp8((int)a.x, false);
            v2f s23 = __builtin_amdgcn_cvt_pk_f32_fp8((int)a.x, true);
            v2f s45 = __builtin_amdgcn_cvt_pk_f32_fp8((int)a.y, false);
            v2f s67 = __builtin_amdgcn_cvt_pk_f32_fp8((int)a.y, true);
            v2f e01 = __builtin_amdgcn_cvt_pk_f32_fp8((int)b.x, false);
            v2f e23 = __builtin_amdgcn_cvt_pk_f32_fp8((int)b.x, true);
            v2f e45 = __builtin_amdgcn_cvt_pk_f32_fp8((int)b.y, false);
            v2f e67 = __builtin_amdgcn_cvt_pk_f32_fp8((int)b.y, true);
            v2f p01 = __builtin_amdgcn_cvt_pk_f32_fp8((int)cc.x, false);
            v2f p23 = __builtin_amdgcn_cvt_pk_f32_fp8((int)cc.x, true);
            v2f p45 = __builtin_amdgcn_cvt_pk_f32_fp8((int)cc.y, false);
            v2f p67 = __builtin_amdgcn_cvt_pk_f32_fp8((int)cc.y, true);
            zs[0] = s01.x + e01.x + p01.x + qv[0];
            zs[1] = s01.y + e01.y + p01.y + qv[1];
            zs[2] = s23.x + e23.x + p23.x + qv[2];
            zs[3] = s23.y + e23.y + p23.y + qv[3];
            zs[4] = s45.x + e45.x + p45.x + qv[4];
            zs[5] = s45.y + e45.y + p45.y + qv[5];
            zs[6] = s67.x + e67.x + p67.x + qv[6];
            zs[7] = s67.y + e67.y + p67.y + qv[7];
#else
            const __hip_bfloat16* Es = (const __hip_bfloat16*)Esv;
            const __hip_bfloat16* Ee = (const __hip_bfloat16*)Eev;
            const __hip_bfloat16* Ep = (const __hip_bfloat16*)Epv;
            uint4 a  = *((const uint4*)(Es + (size_t)i0 * 400) + lane);
            uint4 b  = *((const uint4*)(Ee + (size_t)i2 * 400) + lane);
            uint4 cc = *((const uint4*)(Ep + (size_t)i1 * 400) + lane);
            zs[0] = lo2f(a.x)+lo2f(b.x)+lo2f(cc.x)+qv[0];
            zs[1] = hi2f(a.x)+hi2f(b.x)+hi2f(cc.x)+qv[1];
            zs[2] = lo2f(a.y)+lo2f(b.y)+lo2f(cc.y)+qv[2];
            zs[3] = hi2f(a.y)+hi2f(b.y)+hi2f(cc.y)+qv[3];
            zs[4] = lo2f(a.z)+lo2f(b.z)+lo2f(cc.z)+qv[4];
            zs[5] = hi2f(a.z)+hi2f(b.z)+hi2f(cc.z)+qv[5];
            zs[6] = lo2f(a.w)+lo2f(b.w)+lo2f(cc.w)+qv[6];
            zs[7] = hi2f(a.w)+hi2f(b.w)+hi2f(cc.w)+qv[7];
#endif
#pragma unroll
            for (int jj = 0; jj < 8; jj++) sum = fmaf(fast_tanh(zs[jj]), wv[jj], sum);
        }
#pragma unroll
        for (int off = 32; off; off >>= 1) sum += __shfl_xor(sum, off);
        if (lane == 0) ctx[(size_t)bt * 100 + l] = sum;
    }
}

// ---------- softmax over T: one wave per (b,l) ----------
__global__ __launch_bounds__(256) void softmax_w(
    const float* __restrict__ ctx, float* __restrict__ attn)
{
    int wid = blockIdx.x * 4 + (threadIdx.x >> 6);   // 0..1599
    int lane = threadIdx.x & 63;
    int b = wid / 100, l = wid - b * 100;
    size_t base = (size_t)b * 128 * 100 + l;
    float v0 = ctx[base + (size_t)lane * 100];
    float v1 = ctx[base + (size_t)(lane + 64) * 100];
    float m = fmaxf(v0, v1);
#pragma unroll
    for (int off = 32; off; off >>= 1) m = fmaxf(m, __shfl_xor(m, off));
    float e0 = __expf(v0 - m), e1 = __expf(v1 - m);
    float s = e0 + e1;
#pragma unroll
    for (int off = 32; off; off >>= 1) s += __shfl_xor(s, off);
    float rs = 1.f / s;
    attn[base + (size_t)lane * 100] = e0 * rs;
    attn[base + (size_t)(lane + 64) * 100] = e1 * rs;
}

// ---------- stage C: weighted re-gather -> rnn_bf [2048][512] bf16 ----------
// layout: [first(0:100) | as(100:200) | ae(200:300) | ap(300:400) | first*sa(400:500) | pad 0]
__global__ __launch_bounds__(128) void stage_c(
    const float* __restrict__ x, const float* __restrict__ attn,
    const unsigned short* __restrict__ ENb, const unsigned short* __restrict__ EPb,
    __hip_bfloat16* __restrict__ rnn_bf)
{
    __shared__ float at[100];
    __shared__ int idx[300];
    int bt = blockIdx.x, tid = threadIdx.x;
    if (tid < 100) at[tid] = attn[(size_t)bt * 100 + tid];
    const float* xr = x + (size_t)bt * 400 + 100;
    for (int i = tid; i < 300; i += 128) idx[i] = (int)xr[i];
    __syncthreads();
    int d = tid;
    __hip_bfloat16* o = rnn_bf + (size_t)bt * 512;
    if (d < 100) {
        float as = 0.f, ae = 0.f, ap = 0.f, sa = 0.f;
#pragma unroll 4
        for (int l = 0; l < 100; l++) {
            float a = at[l]; sa += a;
            as = fmaf(a, lo2f(ENb[(size_t)idx[3 * l] * 100 + d]), as);
            ae = fmaf(a, lo2f(ENb[(size_t)idx[3 * l + 2] * 100 + d]), ae);
            ap = fmaf(a, lo2f(EPb[(size_t)idx[3 * l + 1] * 100 + d]), ap);
        }
        float fi = x[(size_t)bt * 400 + d];
        o[d]       = __float2bfloat16(fi);
        o[100 + d] = __float2bfloat16(as);
        o[200 + d] = __float2bfloat16(ae);
        o[300 + d] = __float2bfloat16(ap);
        o[400 + d] = __float2bfloat16(fi * sa);
    } else if (d < 112) {
        o[400 + d] = __float2bfloat16(0.f);   // pad cols 500..511
    }
}

// ---------- X = rnn_bf @ Wih_bf^T + biases, via MFMA ----------
// M=2048 (32 blocks x 64 rows), N=512 (32 col-tiles, paired), K=512 (16 slices).
__global__ __launch_bounds__(256) void gemm_x(
    const __hip_bfloat16* __restrict__ rnn_bf, const __hip_bfloat16* __restrict__ Wih_bf,
    const float* __restrict__ bih, const float* __restrict__ bhh,
    float* __restrict__ X)
{
    int blk = blockIdx.x, tid = threadIdx.x;
    int wave = tid >> 6, lane = tid & 63;
    int cl = lane & 15, kg = lane >> 4;
    int r0 = blk * 64 + wave * 16;

    short8 af[16];
    const __hip_bfloat16* arow = rnn_bf + (size_t)(r0 + cl) * 512 + kg * 8;
#pragma unroll
    for (int ks = 0; ks < 16; ks++) af[ks] = *(const short8*)(arow + ks * 32);

    for (int n0 = 0; n0 < 32; n0 += 2) {
        const __hip_bfloat16* b0 = Wih_bf + (size_t)(n0 * 16 + cl) * 512 + kg * 8;
        const __hip_bfloat16* b1 = b0 + 16 * 512;
        f32x4 acA = (f32x4){0.f, 0.f, 0.f, 0.f};
        f32x4 acB = (f32x4){0.f, 0.f, 0.f, 0.f};
#pragma unroll
        for (int ks = 0; ks < 16; ks++) {
            acA = __builtin_amdgcn_mfma_f32_16x16x32_bf16(af[ks], *(const short8*)(b0 + ks * 32), acA, 0, 0, 0);
            acB = __builtin_amdgcn_mfma_f32_16x16x32_bf16(af[ks], *(const short8*)(b1 + ks * 32), acB, 0, 0, 0);
        }
        int c0 = n0 * 16 + cl, c1 = c0 + 16;
        float bi0 = bih[c0] + bhh[c0];
        float bi1 = bih[c1] + bhh[c1];
#pragma unroll
        for (int r = 0; r < 4; r++) {
            int m = r0 + kg * 4 + r;
            X[(size_t)m * 512 + c0] = acA[r] + bi0;
            X[(size_t)m * 512 + c1] = acB[r] + bi1;
        }
    }
}

// ---------- LSTM via MFMA (R4 structure, proven 76 us) + double-buffered h ----------
__global__ __launch_bounds__(512, 1) void lstm_k(
    const float* __restrict__ X, const __hip_bfloat16* __restrict__ Whh_bf,
    float* __restrict__ hs)
{
    int b = blockIdx.x, tid = threadIdx.x;
    int wave = tid >> 6, lane = tid & 63;
    int col = lane & 15, kg = lane >> 4;

    short8 bf[4][4];
#pragma unroll
    for (int n = 0; n < 4; n++) {
        int g = n * 128 + wave * 16 + col;
#pragma unroll
        for (int kk = 0; kk < 4; kk++)
            bf[n][kk] = *(const short8*)(Whh_bf + (size_t)g * 128 + kk * 32 + kg * 8);
    }

    __shared__ __hip_bfloat16 hbuf[2][128];
    __shared__ float Xs[16][512];
    __shared__ float hsb_s[16][128];
    float c = 0.f;
    if (tid < 128) hbuf[0][tid] = __float2bfloat16(0.f);
    const float* xb = X + (size_t)b * 128 * 512;
    float* hb = hs + (size_t)b * 128 * 128;
    int j = wave * 16 + col;
    int p = 0;

    __syncthreads();

    for (int tc = 0; tc < 8; tc++) {
        {
            const float* src = xb + (size_t)tc * 16 * 512 + tid;
#pragma unroll
            for (int k = 0; k < 16; k++) Xs[k][tid] = src[k * 512];
        }
        __syncthreads();

#pragma unroll 1
        for (int ts = 0; ts < 16; ts++) {
            short8 af[4];
            short8 zz = {};
#pragma unroll
            for (int kk = 0; kk < 4; kk++) {
                af[kk] = zz;
                if (col == 0) af[kk] = *(const short8*)(&hbuf[p][0] + kk * 32 + kg * 8);
            }
            f32x4 acc[4];
#pragma unroll
            for (int n = 0; n < 4; n++) acc[n] = (f32x4){0.f, 0.f, 0.f, 0.f};
#pragma unroll
            for (int kk = 0; kk < 4; kk++)
#pragma unroll
                for (int n = 0; n < 4; n++)
                    acc[n] = __builtin_amdgcn_mfma_f32_16x16x32_bf16(af[kk], bf[n][kk], acc[n], 0, 0, 0);

            if (lane < 16) {
                float pi = acc[0][0] + Xs[ts][j];
                float pf = acc[1][0] + Xs[ts][128 + j];
                float pg = acc[2][0] + Xs[ts][256 + j];
                float po = acc[3][0] + Xs[ts][384 + j];
                c = sigm(pf) * c + sigm(pi) * fast_tanh(pg);
                float hn = sigm(po) * fast_tanh(c);
                hbuf[p ^ 1][j] = __float2bfloat16(hn);
                hsb_s[ts][j] = hn;
            }
            __syncthreads();
            p ^= 1;
        }

        {
            float* dst = hb + (size_t)tc * 16 * 128;
#pragma unroll
            for (int k = 0; k < 4; k++) {
                int i = k * 512 + tid;
                dst[i] = hsb_s[i >> 7][i & 127];
            }
        }
    }
}

__global__ __launch_bounds__(64) void fc_k(
    const float* __restrict__ hs, const float* __restrict__ Wfc,
    const float* __restrict__ bfc, float* __restrict__ out)
{
    int r0 = blockIdx.x * 4, o = threadIdx.x;
    if (o >= 50) return;
    float acc[4] = {0.f, 0.f, 0.f, 0.f};
    for (int j = 0; j < 128; j++) {
        float wv = Wfc[j * 50 + o];
#pragma unroll
        for (int r = 0; r < 4; r++)
            acc[r] = fmaf(hs[(size_t)(r0 + r) * 128 + j], wv, acc[r]);
    }
    float bb = bfc[o];
#pragma unroll
    for (int r = 0; r < 4; r++) out[(size_t)(r0 + r) * 50 + o] = sigm(acc[r] + bb);
}

extern "C" void kernel_launch(void* const* d_in, const int* in_sizes, int n_in,
                              void* d_out, int out_size, void* d_ws, size_t ws_size,
                              hipStream_t stream) {
    const float* x   = (const float*)d_in[0];
    const float* EN  = (const float*)d_in[1];
    const float* EP  = (const float*)d_in[2];
    const float* Wt  = (const float*)d_in[3];
    const float* bt  = (const float*)d_in[4];
    const float* Wa  = (const float*)d_in[5];
    // d_in[6] = b_a: uniform shift along the softmax axis -> cancels, unused.
    const float* Wih = (const float*)d_in[7];
    const float* Whh = (const float*)d_in[8];
    const float* bih = (const float*)d_in[9];
    const float* bhh = (const float*)d_in[10];
    const float* Wfc = (const float*)d_in[11];
    const float* bfc = (const float*)d_in[12];
    float* out = (float*)d_out;

    char* ws = (char*)d_ws;
    size_t off = 0;
    auto alloc = [&](size_t bytes) -> char* {
        char* p = ws + off;
        off = (off + bytes + 255) & ~(size_t)255;
        return p;
    };
    // Tables sized for bf16 worst case; fp8 mode uses half of each.
    void* Es  = (void*)alloc((size_t)VOCAB_ * 400 * 2);
    void* Ee  = (void*)alloc((size_t)VOCAB_ * 400 * 2);
    void* Epb = (void*)alloc((size_t)VOCAB_ * 400 * 2);
    __hip_bfloat16* ENb    = (__hip_bfloat16*)alloc((size_t)VOCAB_ * 100 * 2);
    __hip_bfloat16* EPb    = (__hip_bfloat16*)alloc((size_t)VOCAB_ * 100 * 2);
    __hip_bfloat16* x_bf   = (__hip_bfloat16*)alloc((size_t)BT_ * 100 * 2);
    __hip_bfloat16* WtT    = (__hip_bfloat16*)alloc((size_t)4 * 400 * 128 * 2);
    __hip_bfloat16* Wih_bf = (__hip_bfloat16*)alloc((size_t)512 * 512 * 2);
    __hip_bfloat16* Whh_bf = (__hip_bfloat16*)alloc((size_t)512 * 128 * 2);
    __hip_bfloat16* rnn_bf = (__hip_bfloat16*)alloc((size_t)BT_ * 512 * 2);
    float* q    = (float*)alloc((size_t)BT_ * 400 * 4);
    float* ctx  = (float*)alloc((size_t)BT_ * 100 * 4);
    float* attn = (float*)alloc((size_t)BT_ * 100 * 4);
    float* X    = (float*)alloc((size_t)BT_ * 512 * 4);
    float* hsb  = (float*)alloc((size_t)BT_ * 128 * 4);

    casts_k<<<256, 256, 0, stream>>>(EN, EP, x, Wt, Wih, Whh,
                                     ENb, EPb, x_bf, WtT, Wih_bf, Whh_bf);
    mm_k<<<3 * TBLK + 32, 256, 0, stream>>>(ENb, EPb, x_bf, WtT, bt,
                                            Es, Ee, Epb, q);

    stage_a<<<BT_, 256, 0, stream>>>(x, Es, Ee, Epb, q, Wa, ctx);
    softmax_w<<<400, 256, 0, stream>>>(ctx, attn);
    stage_c<<<BT_, 128, 0, stream>>>(x, attn, (const unsigned short*)ENb,
                                     (const unsigned short*)EPb, rnn_bf);
    gemm_x<<<32, 256, 0, stream>>>(rnn_bf, Wih_bf, bih, bhh, X);
    lstm_k<<<B_, 512, 0, stream>>>(X, Whh_bf, hsb);
    fc_k<<<BT_ / 4, 64, 0, stream>>>(hsb, Wfc, bfc, out);
}